// Round 3
// baseline (408.701 us; speedup 1.0000x reference)
//
#include <hip/hip_runtime.h>

typedef __bf16 bf16;
typedef __bf16 bf16x8 __attribute__((ext_vector_type(8)));
typedef __bf16 bf16x4 __attribute__((ext_vector_type(4)));
typedef float f32x4 __attribute__((ext_vector_type(4)));

#define GLL16(gp, lp)                                                          \
  __builtin_amdgcn_global_load_lds(                                            \
      (const __attribute__((address_space(1))) unsigned int*)(gp),             \
      (__attribute__((address_space(3))) unsigned int*)(lp), 16, 0, 0)

// ------------------------------------------------------- fused fp32->bf16 casts
__global__ __launch_bounds__(256) void cast3_f32_bf16(
    const float* __restrict__ a, bf16* __restrict__ oa, int na4,
    const float* __restrict__ b, bf16* __restrict__ ob, int nb4,
    const float* __restrict__ c, bf16* __restrict__ oc, int nc4) {
  int i = blockIdx.x * blockDim.x + threadIdx.x;
  int stride = gridDim.x * blockDim.x;
  int total = na4 + nb4 + nc4;
  for (; i < total; i += stride) {
    const float4* src;
    bf16x4* dst;
    int j = i;
    if (j < na4) {
      src = (const float4*)a + j; dst = (bf16x4*)oa + j;
    } else if ((j -= na4) < nb4) {
      src = (const float4*)b + j; dst = (bf16x4*)ob + j;
    } else {
      j -= nb4;
      src = (const float4*)c + j; dst = (bf16x4*)oc + j;
    }
    float4 v = *src;
    bf16x4 o;
    o[0] = (bf16)v.x; o[1] = (bf16)v.y; o[2] = (bf16)v.z; o[3] = (bf16)v.w;
    *dst = o;
  }
}

// ---------------------------------------------------------------- GEMM C = A * B^T
// A: MxK bf16 row-major, B: NxK bf16 row-major, C: MxN fp32 (ldc = LDC).
// 128x128 tile, 4 waves (2x2 of 64x64), BK=64, global_load_lds staging,
// XOR-swizzled LDS (16B granules) so fragment ds_read_b128 is 2-way (free).
template <int K, int LDC>
__global__ __launch_bounds__(256) void gemm_bt(
    const bf16* __restrict__ A, const bf16* __restrict__ B,
    float* __restrict__ C) {
  __shared__ __align__(16) bf16 As[128 * 64];
  __shared__ __align__(16) bf16 Bs[128 * 64];
  const int tid  = threadIdx.x;
  const int lane = tid & 63;
  const int wave = tid >> 6;
  const int ln15 = lane & 15, quad = lane >> 4;
  const int wm = wave >> 1, wn = wave & 1;
  const int m0 = blockIdx.y * 128, n0 = blockIdx.x * 128;

  f32x4 acc[4][4] = {};

  for (int k0 = 0; k0 < K; k0 += 64) {
    __syncthreads();
#pragma unroll
    for (int j = 0; j < 4; ++j) {
      int gbase = j * 256 + wave * 64;        // wave-uniform granule base
      int g = gbase + lane;                   // per-lane granule
      int r = g >> 3, c = (g & 7) ^ (r & 7);  // swizzled column granule
      GLL16(A + (size_t)(m0 + r) * K + k0 + c * 8, As + (size_t)gbase * 8);
    }
#pragma unroll
    for (int j = 0; j < 4; ++j) {
      int gbase = j * 256 + wave * 64;
      int g = gbase + lane;
      int r = g >> 3, c = (g & 7) ^ (r & 7);
      GLL16(B + (size_t)(n0 + r) * K + k0 + c * 8, Bs + (size_t)gbase * 8);
    }
    __syncthreads();
#pragma unroll
    for (int kk = 0; kk < 2; ++kk) {
      bf16x8 af[4], bfr[4];
#pragma unroll
      for (int mi = 0; mi < 4; ++mi) {
        int m = wm * 64 + mi * 16 + ln15;
        int cg = kk * 4 + quad;
        af[mi] = *(const bf16x8*)(As + (m * 8 + (cg ^ (m & 7))) * 8);
      }
#pragma unroll
      for (int ni = 0; ni < 4; ++ni) {
        int n = wn * 64 + ni * 16 + ln15;
        int cg = kk * 4 + quad;
        bfr[ni] = *(const bf16x8*)(Bs + (n * 8 + (cg ^ (n & 7))) * 8);
      }
#pragma unroll
      for (int mi = 0; mi < 4; ++mi)
#pragma unroll
        for (int ni = 0; ni < 4; ++ni)
          acc[mi][ni] = __builtin_amdgcn_mfma_f32_16x16x32_bf16(
              af[mi], bfr[ni], acc[mi][ni], 0, 0, 0);
    }
  }
#pragma unroll
  for (int mi = 0; mi < 4; ++mi)
#pragma unroll
    for (int ni = 0; ni < 4; ++ni)
#pragma unroll
      for (int r = 0; r < 4; ++r) {
        int row = m0 + wm * 64 + mi * 16 + quad * 4 + r;  // C/D: row=(lane>>4)*4+reg
        int col = n0 + wn * 64 + ni * 16 + ln15;          //      col=lane&15
        C[(size_t)row * LDC + col] = acc[mi][ni][r];
      }
}

// ---------------------------------------------------------------- qkv epilogue
// RMSNorm + rotary on q,k (q additionally scaled by ATTN_SCALE=0.12);
// v = l0*v + l1*ve transposed -> bf16 vt [H][128][T].
__global__ __launch_bounds__(256) void qkv_post(
    const float* __restrict__ qkv, const float* __restrict__ ve,
    const float* __restrict__ lambdas, bf16* __restrict__ qn,
    bf16* __restrict__ kn, bf16* __restrict__ vt) {
  const int h  = blockIdx.x;       // 0..7
  const int t0 = blockIdx.y * 64;  // 64 rows per block
  const int tid = threadIdx.x;
  const int wave = tid >> 6, lane = tid & 63;
  __shared__ __align__(16) float tile[64][129];  // +1 pad: conflict-free transpose

  // Phase A: q/k rms+rotary. Lane j holds the rotary pair (d=j, d=j+64).
  const int j = lane;
  float cth = 1.0f, sth = 0.0f;
  for (int i = 0; i < 16; ++i) {
    int t = t0 + wave * 16 + i;
    if (j < 32) {
      float ang = exp2f((float)j * (-10.0f / 31.0f));  // (1/1024)^(j/31)
      float th = (float)t * ang;
      __sincosf(th, &sth, &cth);
    }
#pragma unroll
    for (int qk = 0; qk < 2; ++qk) {
      const float* row = qkv + (size_t)t * 3072 + qk * 1024 + h * 128;
      float x1 = row[j], x2 = row[j + 64];
      float ss = x1 * x1 + x2 * x2;
#pragma unroll
      for (int m = 1; m < 64; m <<= 1) ss += __shfl_xor(ss, m, 64);
      float rinv = rsqrtf(ss * (1.0f / 128.0f) + 1.1920929e-7f);
      if (qk == 0) rinv *= 0.12f;  // fold ATTN_SCALE into q
      float y1 = (x1 * cth + x2 * sth) * rinv;
      float y2 = (x2 * cth - x1 * sth) * rinv;
      bf16* orow = (qk == 0 ? qn : kn) + (size_t)t * 1024 + h * 128;
      orow[j] = (bf16)y1;
      orow[j + 64] = (bf16)y2;
    }
  }

  // Phase B: v merge + transpose through LDS.
  float l0 = lambdas[0], l1 = lambdas[1];
  for (int c = 0; c < 32; ++c) {
    int idx = c * 256 + tid;
    int d = idx & 127, tl = idx >> 7;
    int t = t0 + tl;
    float v = qkv[(size_t)t * 3072 + 2048 + h * 128 + d];
    float vev = ve[(size_t)t * 1024 + h * 128 + d];
    tile[tl][d] = l0 * v + l1 * vev;
  }
  __syncthreads();
  for (int c = 0; c < 32; ++c) {
    int idx = c * 256 + tid;
    int tl = idx & 63, d = idx >> 6;
    vt[((size_t)(h * 128 + d)) * 4096 + t0 + tl] = (bf16)tile[tl][d];
  }
}

// ---------------------------------------------------------------- flash attention
// BM=BN=64, Hd=128. 512 blocks (one q-tile each), 4 waves x 16 q-rows.
// NO barriers, NO LDS staging: K/V fragments loaded directly from global into
// B-layout registers (16B per lane per frag; 16 rows x 64B lines per load;
// the 4 waves issue identical addresses -> L1 reuse).
// NO online softmax: q,k are RMS-normalized so |S| <= 0.12*128 = 15.36 -> raw
// exp(S) <= 4.9e6, row sums <= 2e10: fp32-safe without max subtraction.
// l-reduction deferred: per-lane partials, ONE shuffle reduce after the loop.
__global__ __launch_bounds__(256) void flash_attn(
    const bf16* __restrict__ qn, const bf16* __restrict__ kn,
    const bf16* __restrict__ vt, bf16* __restrict__ y) {
  const int halfg = blockIdx.x >> 8;   // 0: big tiles first
  const int idx = blockIdx.x & 255;
  const int h = idx & 7;
  const int p = idx >> 3;              // 0..31
  const int qtile = halfg ? p : 63 - p;
  const int tid = threadIdx.x;
  const int wave = tid >> 6, lane = tid & 63;
  const int ln15 = lane & 15, quad = lane >> 4;

  __shared__ __align__(16) bf16 Ps[4 * 16 * 64];  // per-wave P, 8-gran swizzle
  bf16* Pw = Ps + wave * 16 * 64;

  const int q0 = qtile * 64;
  const int nkv = qtile + 1;
  const int myrow = wave * 16 + quad * 4;  // +r

  // Q fragments (A-layout: m=lane&15, k=quad*8+j). qn is pre-scaled by 0.12.
  bf16x8 qf[4];
  {
    const bf16* qb =
        qn + (size_t)(q0 + wave * 16 + ln15) * 1024 + h * 128 + quad * 8;
#pragma unroll
    for (int ks = 0; ks < 4; ++ks) qf[ks] = *(const bf16x8*)(qb + ks * 32);
  }
  f32x4 acc_o[8] = {};
  float rs[4] = {0.f, 0.f, 0.f, 0.f};

  const bf16* kbase = kn + h * 128 + (size_t)ln15 * 1024 + quad * 8;
  const bf16* vbase = vt + ((size_t)(h * 128 + ln15)) * 4096 + quad * 8;

  for (int kt = 0; kt < nkv; ++kt) {
    const int kv0 = kt * 64;

    // K B-frags straight from global: B[k=d][n=kv], n=ln15, k=quad*8+j.
    bf16x8 kf[4][4];
#pragma unroll
    for (int nf = 0; nf < 4; ++nf)
#pragma unroll
      for (int ks = 0; ks < 4; ++ks)
        kf[ks][nf] =
            *(const bf16x8*)(kbase + (size_t)(kv0 + nf * 16) * 1024 + ks * 32);

    f32x4 accs[4] = {};
#pragma unroll
    for (int ks = 0; ks < 4; ++ks)
#pragma unroll
      for (int nf = 0; nf < 4; ++nf)
        accs[nf] =
            __builtin_amdgcn_mfma_f32_16x16x32_bf16(qf[ks], kf[ks][nf], accs[nf], 0, 0, 0);

    // V^T B-frags: B[k=kv][n=d], n=ln15(+16*nf2), k=quad*8+j (+32*ks2).
    bf16x8 vf[2][8];
#pragma unroll
    for (int nf2 = 0; nf2 < 8; ++nf2)
#pragma unroll
      for (int ks2 = 0; ks2 < 2; ++ks2)
        vf[ks2][nf2] =
            *(const bf16x8*)(vbase + (size_t)(nf2 * 16) * 4096 + kv0 + ks2 * 32);

    // p = exp(S); causal mask on the diagonal tile sets p=0.
    const bool diag = (kt == nkv - 1);
#pragma unroll
    for (int nf = 0; nf < 4; ++nf)
#pragma unroll
      for (int r = 0; r < 4; ++r) {
        float pe = __expf(accs[nf][r]);
        if (diag && (nf * 16 + ln15 > myrow + r)) pe = 0.f;
        rs[r] += pe;
        int mr = quad * 4 + r, n = nf * 16 + ln15;
        Pw[(mr * 8 + ((n >> 3) ^ (mr & 7))) * 8 + (n & 7)] = (bf16)pe;
      }

    // O += P V (P via per-wave LDS roundtrip into A-layout).
#pragma unroll
    for (int ks2 = 0; ks2 < 2; ++ks2) {
      bf16x8 a =
          *(const bf16x8*)(Pw + (ln15 * 8 + ((ks2 * 4 + quad) ^ (ln15 & 7))) * 8);
#pragma unroll
      for (int nf2 = 0; nf2 < 8; ++nf2)
        acc_o[nf2] =
            __builtin_amdgcn_mfma_f32_16x16x32_bf16(a, vf[ks2][nf2], acc_o[nf2], 0, 0, 0);
    }
  }

  // One deferred l-reduction over the 16 lanes holding each row's columns.
#pragma unroll
  for (int m = 1; m < 16; m <<= 1)
#pragma unroll
    for (int r = 0; r < 4; ++r) rs[r] += __shfl_xor(rs[r], m, 64);
  float inv[4];
#pragma unroll
  for (int r = 0; r < 4; ++r) inv[r] = 1.0f / rs[r];

#pragma unroll
  for (int nf2 = 0; nf2 < 8; ++nf2)
#pragma unroll
    for (int r = 0; r < 4; ++r) {
      int t = q0 + myrow + r;
      int col = nf2 * 16 + ln15;
      y[(size_t)t * 1024 + h * 128 + col] = (bf16)(acc_o[nf2][r] * inv[r]);
    }
}

// ---------------------------------------------------------------- launch
extern "C" void kernel_launch(void* const* d_in, const int* in_sizes, int n_in,
                              void* d_out, int out_size, void* d_ws,
                              size_t ws_size, hipStream_t stream) {
  const float* x       = (const float*)d_in[0];  // [1,4096,1024]
  const float* ve      = (const float*)d_in[1];  // [1,4096,1024]
  const float* qkv_w   = (const float*)d_in[2];  // [3,1024,1024]
  const float* lambdas = (const float*)d_in[3];  // [2]
  const float* c_proj  = (const float*)d_in[4];  // [1024,1024]
  float* out = (float*)d_out;                    // [1,4096,1024] fp32

  char* ws = (char*)d_ws;
  float* qkv  = (float*)ws;                   // 4096*3072 f32 = 48 MiB
  bf16* xbf   = (bf16*)(ws + 50331648);       // 8 MiB
  bf16* wqkv  = (bf16*)(ws + 58720256);       // 6 MiB
  bf16* wproj = (bf16*)(ws + 65011712);       // 2 MiB
  bf16* qn    = (bf16*)(ws + 67108864);       // 8 MiB
  bf16* kn    = (bf16*)(ws + 75497472);       // 8 MiB
  bf16* vt    = (bf16*)(ws + 83886080);       // 8 MiB  [H][128][T]
  bf16* yb    = (bf16*)(ws + 92274688);       // 8 MiB  (total ~96 MiB)

  cast3_f32_bf16<<<2048, 256, 0, stream>>>(x, xbf, 4194304 / 4, qkv_w, wqkv,
                                           3145728 / 4, c_proj, wproj,
                                           1048576 / 4);

  gemm_bt<1024, 3072><<<dim3(24, 32), 256, 0, stream>>>(xbf, wqkv, qkv);

  qkv_post<<<dim3(8, 64), 256, 0, stream>>>(qkv, ve, lambdas, qn, kn, vt);

  flash_attn<<<512, 256, 0, stream>>>(qn, kn, vt, yb);

  gemm_bt<1024, 1024><<<dim3(8, 32), 256, 0, stream>>>(yb, wproj, out);
}

// Round 4
// 276.696 us; speedup vs baseline: 1.4771x; 1.4771x over previous
//
#include <hip/hip_runtime.h>

typedef __bf16 bf16;
typedef __bf16 bf16x8 __attribute__((ext_vector_type(8)));
typedef __bf16 bf16x4 __attribute__((ext_vector_type(4)));
typedef float f32x4 __attribute__((ext_vector_type(4)));

#define GLL16(gp, lp)                                                          \
  __builtin_amdgcn_global_load_lds(                                            \
      (const __attribute__((address_space(1))) unsigned int*)(gp),             \
      (__attribute__((address_space(3))) unsigned int*)(lp), 16, 0, 0)

// ------------------------------------------------------- fused fp32->bf16 casts
__global__ __launch_bounds__(256) void cast3_f32_bf16(
    const float* __restrict__ a, bf16* __restrict__ oa, int na4,
    const float* __restrict__ b, bf16* __restrict__ ob, int nb4,
    const float* __restrict__ c, bf16* __restrict__ oc, int nc4) {
  int i = blockIdx.x * blockDim.x + threadIdx.x;
  int stride = gridDim.x * blockDim.x;
  int total = na4 + nb4 + nc4;
  for (; i < total; i += stride) {
    const float4* src;
    bf16x4* dst;
    int j = i;
    if (j < na4) {
      src = (const float4*)a + j; dst = (bf16x4*)oa + j;
    } else if ((j -= na4) < nb4) {
      src = (const float4*)b + j; dst = (bf16x4*)ob + j;
    } else {
      j -= nb4;
      src = (const float4*)c + j; dst = (bf16x4*)oc + j;
    }
    float4 v = *src;
    bf16x4 o;
    o[0] = (bf16)v.x; o[1] = (bf16)v.y; o[2] = (bf16)v.z; o[3] = (bf16)v.w;
    *dst = o;
  }
}

// ---------------------------------------------------------------- GEMM C = A * B^T
template <int K, int LDC>
__global__ __launch_bounds__(256) void gemm_bt(
    const bf16* __restrict__ A, const bf16* __restrict__ B,
    float* __restrict__ C) {
  __shared__ __align__(16) bf16 As[128 * 64];
  __shared__ __align__(16) bf16 Bs[128 * 64];
  const int tid  = threadIdx.x;
  const int lane = tid & 63;
  const int wave = tid >> 6;
  const int ln15 = lane & 15, quad = lane >> 4;
  const int wm = wave >> 1, wn = wave & 1;
  const int m0 = blockIdx.y * 128, n0 = blockIdx.x * 128;

  f32x4 acc[4][4] = {};

  for (int k0 = 0; k0 < K; k0 += 64) {
    __syncthreads();
#pragma unroll
    for (int j = 0; j < 4; ++j) {
      int gbase = j * 256 + wave * 64;
      int g = gbase + lane;
      int r = g >> 3, c = (g & 7) ^ (r & 7);
      GLL16(A + (size_t)(m0 + r) * K + k0 + c * 8, As + (size_t)gbase * 8);
    }
#pragma unroll
    for (int j = 0; j < 4; ++j) {
      int gbase = j * 256 + wave * 64;
      int g = gbase + lane;
      int r = g >> 3, c = (g & 7) ^ (r & 7);
      GLL16(B + (size_t)(n0 + r) * K + k0 + c * 8, Bs + (size_t)gbase * 8);
    }
    __syncthreads();
#pragma unroll
    for (int kk = 0; kk < 2; ++kk) {
      bf16x8 af[4], bfr[4];
#pragma unroll
      for (int mi = 0; mi < 4; ++mi) {
        int m = wm * 64 + mi * 16 + ln15;
        int cg = kk * 4 + quad;
        af[mi] = *(const bf16x8*)(As + (m * 8 + (cg ^ (m & 7))) * 8);
      }
#pragma unroll
      for (int ni = 0; ni < 4; ++ni) {
        int n = wn * 64 + ni * 16 + ln15;
        int cg = kk * 4 + quad;
        bfr[ni] = *(const bf16x8*)(Bs + (n * 8 + (cg ^ (n & 7))) * 8);
      }
#pragma unroll
      for (int mi = 0; mi < 4; ++mi)
#pragma unroll
        for (int ni = 0; ni < 4; ++ni)
          acc[mi][ni] = __builtin_amdgcn_mfma_f32_16x16x32_bf16(
              af[mi], bfr[ni], acc[mi][ni], 0, 0, 0);
    }
  }
#pragma unroll
  for (int mi = 0; mi < 4; ++mi)
#pragma unroll
    for (int ni = 0; ni < 4; ++ni)
#pragma unroll
      for (int r = 0; r < 4; ++r) {
        int row = m0 + wm * 64 + mi * 16 + quad * 4 + r;
        int col = n0 + wn * 64 + ni * 16 + ln15;
        C[(size_t)row * LDC + col] = acc[mi][ni][r];
      }
}

// ---------------------------------------------------------------- qkv epilogue
__global__ __launch_bounds__(256) void qkv_post(
    const float* __restrict__ qkv, const float* __restrict__ ve,
    const float* __restrict__ lambdas, bf16* __restrict__ qn,
    bf16* __restrict__ kn, bf16* __restrict__ vt) {
  const int h  = blockIdx.x;
  const int t0 = blockIdx.y * 64;
  const int tid = threadIdx.x;
  const int wave = tid >> 6, lane = tid & 63;
  __shared__ __align__(16) float tile[64][129];

  const int j = lane;
  float cth = 1.0f, sth = 0.0f;
  for (int i = 0; i < 16; ++i) {
    int t = t0 + wave * 16 + i;
    if (j < 32) {
      float ang = exp2f((float)j * (-10.0f / 31.0f));
      float th = (float)t * ang;
      __sincosf(th, &sth, &cth);
    }
#pragma unroll
    for (int qk = 0; qk < 2; ++qk) {
      const float* row = qkv + (size_t)t * 3072 + qk * 1024 + h * 128;
      float x1 = row[j], x2 = row[j + 64];
      float ss = x1 * x1 + x2 * x2;
#pragma unroll
      for (int m = 1; m < 64; m <<= 1) ss += __shfl_xor(ss, m, 64);
      float rinv = rsqrtf(ss * (1.0f / 128.0f) + 1.1920929e-7f);
      if (qk == 0) rinv *= 0.12f;  // fold ATTN_SCALE into q
      float y1 = (x1 * cth + x2 * sth) * rinv;
      float y2 = (x2 * cth - x1 * sth) * rinv;
      bf16* orow = (qk == 0 ? qn : kn) + (size_t)t * 1024 + h * 128;
      orow[j] = (bf16)y1;
      orow[j + 64] = (bf16)y2;
    }
  }

  float l0 = lambdas[0], l1 = lambdas[1];
  for (int c = 0; c < 32; ++c) {
    int idx = c * 256 + tid;
    int d = idx & 127, tl = idx >> 7;
    int t = t0 + tl;
    float v = qkv[(size_t)t * 3072 + 2048 + h * 128 + d];
    float vev = ve[(size_t)t * 1024 + h * 128 + d];
    tile[tl][d] = l0 * v + l1 * vev;
  }
  __syncthreads();
  for (int c = 0; c < 32; ++c) {
    int idx = c * 256 + tid;
    int tl = idx & 63, d = idx >> 6;
    vt[((size_t)(h * 128 + d)) * 4096 + t0 + tl] = (bf16)tile[tl][d];
  }
}

// ---------------------------------------------------------------- flash attention
// S^T formulation: S^T = K Q^T (A=K-frags from LDS, B=Q-frags in regs), so each
// lane's 4 P values are CONSECUTIVE kv at fixed q -> packed b64 P^T store + b128
// B-frag reload (no 64x scalar b16 writes, no in-loop shuffles). O^T = V^T P^T.
// Softmax: |S| <= 0.12*128 = 15.36 (rms-normed q,k) -> raw exp, deferred scalar
// l per lane, ONE cross-quad reduce at the end. GLL16 double-buffered K/V,
// one barrier per kv-iter. 512 blocks, snake-paired qtiles for CU balance.
__global__ __launch_bounds__(256) void flash_attn(
    const bf16* __restrict__ qn, const bf16* __restrict__ kn,
    const bf16* __restrict__ vt, bf16* __restrict__ y) {
  const int halfg = blockIdx.x >> 8;
  const int idx = blockIdx.x & 255;
  const int h = idx & 7;
  const int p = idx >> 3;
  const int qtile = halfg ? p : 63 - p;
  const int tid = threadIdx.x;
  const int wave = tid >> 6, lane = tid & 63;
  const int ln15 = lane & 15, quad = lane >> 4;

  __shared__ __align__(16) bf16 Ks[2 * 64 * 128];  // [buf][kv][d], 16-gran swizzle
  __shared__ __align__(16) bf16 Vs[2 * 128 * 64];  // [buf][d][kv], 8-gran swizzle
  __shared__ __align__(16) bf16 Ps[4 * 16 * 64];   // per-wave P^T [q=16][kv=64]
  bf16* Pw = Ps + wave * 16 * 64;

  const int q0 = qtile * 64;
  const int nkv = qtile + 1;
  const int q = q0 + wave * 16 + ln15;  // this lane's q (column of S^T)

  // Q B-frags: B[k=d][n=q]: lane n=ln15 -> q, k=quad*8+j -> d (+32*ks).
  bf16x8 qf[4];
  {
    const bf16* qb = qn + (size_t)q * 1024 + h * 128 + quad * 8;
#pragma unroll
    for (int ks = 0; ks < 4; ++ks) qf[ks] = *(const bf16x8*)(qb + ks * 32);
  }
  f32x4 acc_o[8] = {};
  float rs = 0.0f;

  auto prefetch = [&](int kt, int buf) {
    const int kv0 = kt * 64;
    bf16* ks = Ks + buf * (64 * 128);
    bf16* vs = Vs + buf * (128 * 64);
#pragma unroll
    for (int jj = 0; jj < 4; ++jj) {  // K tile: 64 rows x 16 granules
      int gbase = jj * 256 + wave * 64;
      int g = gbase + lane;
      int r = g >> 4, c = (g & 15) ^ (r & 15);
      GLL16(kn + (size_t)(kv0 + r) * 1024 + h * 128 + c * 8,
            ks + (size_t)gbase * 8);
    }
#pragma unroll
    for (int jj = 0; jj < 4; ++jj) {  // V^T tile: 128 rows x 8 granules
      int gbase = jj * 256 + wave * 64;
      int g = gbase + lane;
      int d = g >> 3, c = (g & 7) ^ (d & 7);
      GLL16(vt + ((size_t)(h * 128 + d)) * 4096 + kv0 + c * 8,
            vs + (size_t)gbase * 8);
    }
  };

  prefetch(0, 0);

  for (int kt = 0; kt < nkv; ++kt) {
    const int kv0 = kt * 64;
    __syncthreads();  // drains prefetch for buf[kt&1]; gates buffer reuse
    if (kt + 1 < nkv) prefetch(kt + 1, (kt + 1) & 1);
    const bf16* ksb = Ks + (kt & 1) * (64 * 128);
    const bf16* vsb = Vs + (kt & 1) * (128 * 64);

    // S^T = K Q^T: A-frag [m=kv_local][k=d] from Ks; 4 kv-tiles (nf) x 4 ks.
    f32x4 accs[4] = {};
#pragma unroll
    for (int ks = 0; ks < 4; ++ks)
#pragma unroll
      for (int nf = 0; nf < 4; ++nf) {
        int row = nf * 16 + ln15;           // kv_local (A-operand m=ln15)
        int sg = (4 * ks + quad) ^ ln15;    // swizzled d-granule
        bf16x8 a = *(const bf16x8*)(ksb + (row * 16 + sg) * 8);
        accs[nf] =
            __builtin_amdgcn_mfma_f32_16x16x32_bf16(a, qf[ks], accs[nf], 0, 0, 0);
      }

    // exp + causal mask + packed P^T store (4 consecutive kv per lane per nf).
    const bool diag = (kt == nkv - 1);
#pragma unroll
    for (int nf = 0; nf < 4; ++nf) {
      bf16x4 pk;
#pragma unroll
      for (int r = 0; r < 4; ++r) {
        float pe = __expf(accs[nf][r]);
        int kv_l = nf * 16 + quad * 4 + r;  // C-layout: row = quad*4+reg
        if (diag && kv0 + kv_l > q) pe = 0.0f;
        rs += pe;
        pk[r] = (bf16)pe;
      }
      int kvg = 2 * nf + (quad >> 1);       // kv-granule of these 4 values
      int sg = kvg ^ (ln15 & 7);
      *(bf16x4*)(Pw + (ln15 * 8 + sg) * 8 + 4 * (quad & 1)) = pk;
    }

    // O^T += V^T P^T: A-frag [m=d][k=kv] from Vs; B-frag P^T b128 from Pw.
#pragma unroll
    for (int ks2 = 0; ks2 < 2; ++ks2) {
      int psg = (4 * ks2 + quad) ^ (ln15 & 7);
      bf16x8 pf = *(const bf16x8*)(Pw + (ln15 * 8 + psg) * 8);
#pragma unroll
      for (int mf = 0; mf < 8; ++mf) {
        int row = mf * 16 + ln15;           // d (A-operand m=ln15)
        int vg = (4 * ks2 + quad) ^ (ln15 & 7);
        bf16x8 a = *(const bf16x8*)(vsb + (row * 8 + vg) * 8);
        acc_o[mf] =
            __builtin_amdgcn_mfma_f32_16x16x32_bf16(a, pf, acc_o[mf], 0, 0, 0);
      }
    }
  }

  // l(q) = sum over the 4 quads' partials; all lanes of a q-column agree.
  rs += __shfl_xor(rs, 16, 64);
  rs += __shfl_xor(rs, 32, 64);
  float inv = 1.0f / rs;

  // O^T C-layout: m = d_local = 16*mf + quad*4 + r, n = q = ln15.
  bf16* yb_ = y + (size_t)q * 1024 + h * 128 + quad * 4;
#pragma unroll
  for (int mf = 0; mf < 8; ++mf) {
    bf16x4 o;
#pragma unroll
    for (int r = 0; r < 4; ++r) o[r] = (bf16)(acc_o[mf][r] * inv);
    *(bf16x4*)(yb_ + mf * 16) = o;
  }
}

// ---------------------------------------------------------------- launch
extern "C" void kernel_launch(void* const* d_in, const int* in_sizes, int n_in,
                              void* d_out, int out_size, void* d_ws,
                              size_t ws_size, hipStream_t stream) {
  const float* x       = (const float*)d_in[0];  // [1,4096,1024]
  const float* ve      = (const float*)d_in[1];  // [1,4096,1024]
  const float* qkv_w   = (const float*)d_in[2];  // [3,1024,1024]
  const float* lambdas = (const float*)d_in[3];  // [2]
  const float* c_proj  = (const float*)d_in[4];  // [1024,1024]
  float* out = (float*)d_out;                    // [1,4096,1024] fp32

  char* ws = (char*)d_ws;
  float* qkv  = (float*)ws;                   // 48 MiB
  bf16* xbf   = (bf16*)(ws + 50331648);       // 8 MiB
  bf16* wqkv  = (bf16*)(ws + 58720256);       // 6 MiB
  bf16* wproj = (bf16*)(ws + 65011712);       // 2 MiB
  bf16* qn    = (bf16*)(ws + 67108864);       // 8 MiB
  bf16* kn    = (bf16*)(ws + 75497472);       // 8 MiB
  bf16* vt    = (bf16*)(ws + 83886080);       // 8 MiB  [H][128][T]
  bf16* yb    = (bf16*)(ws + 92274688);       // 8 MiB

  cast3_f32_bf16<<<2048, 256, 0, stream>>>(x, xbf, 4194304 / 4, qkv_w, wqkv,
                                           3145728 / 4, c_proj, wproj,
                                           1048576 / 4);

  gemm_bt<1024, 3072><<<dim3(24, 32), 256, 0, stream>>>(xbf, wqkv, qkv);

  qkv_post<<<dim3(8, 64), 256, 0, stream>>>(qkv, ve, lambdas, qn, kn, vt);

  flash_attn<<<512, 256, 0, stream>>>(qn, kn, vt, yb);

  gemm_bt<1024, 1024><<<dim3(8, 32), 256, 0, stream>>>(yb, wproj, out);
}

// Round 5
// 255.081 us; speedup vs baseline: 1.6022x; 1.0847x over previous
//
#include <hip/hip_runtime.h>

typedef __bf16 bf16;
typedef __bf16 bf16x8 __attribute__((ext_vector_type(8)));
typedef __bf16 bf16x4 __attribute__((ext_vector_type(4)));
typedef float f32x4 __attribute__((ext_vector_type(4)));

#define GLL16(gp, lp)                                                          \
  __builtin_amdgcn_global_load_lds(                                            \
      (const __attribute__((address_space(1))) unsigned int*)(gp),             \
      (__attribute__((address_space(3))) unsigned int*)(lp), 16, 0, 0)

// ------------------------------------------------------- fused fp32->bf16 casts
__global__ __launch_bounds__(256) void cast3_f32_bf16(
    const float* __restrict__ a, bf16* __restrict__ oa, int na4,
    const float* __restrict__ b, bf16* __restrict__ ob, int nb4,
    const float* __restrict__ c, bf16* __restrict__ oc, int nc4) {
  int i = blockIdx.x * blockDim.x + threadIdx.x;
  int stride = gridDim.x * blockDim.x;
  int total = na4 + nb4 + nc4;
  for (; i < total; i += stride) {
    const float4* src;
    bf16x4* dst;
    int j = i;
    if (j < na4) {
      src = (const float4*)a + j; dst = (bf16x4*)oa + j;
    } else if ((j -= na4) < nb4) {
      src = (const float4*)b + j; dst = (bf16x4*)ob + j;
    } else {
      j -= nb4;
      src = (const float4*)c + j; dst = (bf16x4*)oc + j;
    }
    float4 v = *src;
    bf16x4 o;
    o[0] = (bf16)v.x; o[1] = (bf16)v.y; o[2] = (bf16)v.z; o[3] = (bf16)v.w;
    *dst = o;
  }
}

// ---------------------------------------------------------------- GEMM C = A * B^T
// Output type templated: fp32 for the final projection, bf16 for qkv (halves
// the HBM round-trip into qkv_post; rmsnorm tolerance is ample).
template <int K, int LDC, typename CT>
__global__ __launch_bounds__(256) void gemm_bt(
    const bf16* __restrict__ A, const bf16* __restrict__ B,
    CT* __restrict__ C) {
  __shared__ __align__(16) bf16 As[128 * 64];
  __shared__ __align__(16) bf16 Bs[128 * 64];
  const int tid  = threadIdx.x;
  const int lane = tid & 63;
  const int wave = tid >> 6;
  const int ln15 = lane & 15, quad = lane >> 4;
  const int wm = wave >> 1, wn = wave & 1;
  const int m0 = blockIdx.y * 128, n0 = blockIdx.x * 128;

  f32x4 acc[4][4] = {};

  for (int k0 = 0; k0 < K; k0 += 64) {
    __syncthreads();
#pragma unroll
    for (int j = 0; j < 4; ++j) {
      int gbase = j * 256 + wave * 64;
      int g = gbase + lane;
      int r = g >> 3, c = (g & 7) ^ (r & 7);
      GLL16(A + (size_t)(m0 + r) * K + k0 + c * 8, As + (size_t)gbase * 8);
    }
#pragma unroll
    for (int j = 0; j < 4; ++j) {
      int gbase = j * 256 + wave * 64;
      int g = gbase + lane;
      int r = g >> 3, c = (g & 7) ^ (r & 7);
      GLL16(B + (size_t)(n0 + r) * K + k0 + c * 8, Bs + (size_t)gbase * 8);
    }
    __syncthreads();
#pragma unroll
    for (int kk = 0; kk < 2; ++kk) {
      bf16x8 af[4], bfr[4];
#pragma unroll
      for (int mi = 0; mi < 4; ++mi) {
        int m = wm * 64 + mi * 16 + ln15;
        int cg = kk * 4 + quad;
        af[mi] = *(const bf16x8*)(As + (m * 8 + (cg ^ (m & 7))) * 8);
      }
#pragma unroll
      for (int ni = 0; ni < 4; ++ni) {
        int n = wn * 64 + ni * 16 + ln15;
        int cg = kk * 4 + quad;
        bfr[ni] = *(const bf16x8*)(Bs + (n * 8 + (cg ^ (n & 7))) * 8);
      }
#pragma unroll
      for (int mi = 0; mi < 4; ++mi)
#pragma unroll
        for (int ni = 0; ni < 4; ++ni)
          acc[mi][ni] = __builtin_amdgcn_mfma_f32_16x16x32_bf16(
              af[mi], bfr[ni], acc[mi][ni], 0, 0, 0);
    }
  }
#pragma unroll
  for (int mi = 0; mi < 4; ++mi)
#pragma unroll
    for (int ni = 0; ni < 4; ++ni)
#pragma unroll
      for (int r = 0; r < 4; ++r) {
        int row = m0 + wm * 64 + mi * 16 + quad * 4 + r;
        int col = n0 + wn * 64 + ni * 16 + ln15;
        C[(size_t)row * LDC + col] = (CT)acc[mi][ni][r];
      }
}

// ---------------------------------------------------------------- qkv epilogue
// qkv is now bf16. RMSNorm + rotary on q,k (q pre-scaled by 0.12);
// v = l0*v + l1*ve transposed -> bf16 vt [H][128][T].
__global__ __launch_bounds__(256) void qkv_post(
    const bf16* __restrict__ qkv, const float* __restrict__ ve,
    const float* __restrict__ lambdas, bf16* __restrict__ qn,
    bf16* __restrict__ kn, bf16* __restrict__ vt) {
  const int h  = blockIdx.x;
  const int t0 = blockIdx.y * 64;
  const int tid = threadIdx.x;
  const int wave = tid >> 6, lane = tid & 63;
  __shared__ __align__(16) float tile[64][129];

  const int j = lane;
  float cth = 1.0f, sth = 0.0f;
  for (int i = 0; i < 16; ++i) {
    int t = t0 + wave * 16 + i;
    if (j < 32) {
      float ang = exp2f((float)j * (-10.0f / 31.0f));
      float th = (float)t * ang;
      __sincosf(th, &sth, &cth);
    }
#pragma unroll
    for (int qk = 0; qk < 2; ++qk) {
      const bf16* row = qkv + (size_t)t * 3072 + qk * 1024 + h * 128;
      float x1 = (float)row[j], x2 = (float)row[j + 64];
      float ss = x1 * x1 + x2 * x2;
#pragma unroll
      for (int m = 1; m < 64; m <<= 1) ss += __shfl_xor(ss, m, 64);
      float rinv = rsqrtf(ss * (1.0f / 128.0f) + 1.1920929e-7f);
      if (qk == 0) rinv *= 0.12f;  // fold ATTN_SCALE into q
      float y1 = (x1 * cth + x2 * sth) * rinv;
      float y2 = (x2 * cth - x1 * sth) * rinv;
      bf16* orow = (qk == 0 ? qn : kn) + (size_t)t * 1024 + h * 128;
      orow[j] = (bf16)y1;
      orow[j + 64] = (bf16)y2;
    }
  }

  float l0 = lambdas[0], l1 = lambdas[1];
  for (int c = 0; c < 32; ++c) {
    int idx = c * 256 + tid;
    int d = idx & 127, tl = idx >> 7;
    int t = t0 + tl;
    float v = (float)qkv[(size_t)t * 3072 + 2048 + h * 128 + d];
    float vev = ve[(size_t)t * 1024 + h * 128 + d];
    tile[tl][d] = l0 * v + l1 * vev;
  }
  __syncthreads();
  for (int c = 0; c < 32; ++c) {
    int idx = c * 256 + tid;
    int tl = idx & 63, d = idx >> 6;
    vt[((size_t)(h * 128 + d)) * 4096 + t0 + tl] = (bf16)tile[tl][d];
  }
}

// ---------------------------------------------------------------- flash attention
// Work-split (not duplicated) across waves to cut LDS traffic 2x:
//  phase 1: wave w computes S^T[kv-slice w*16..+15][all 64 q]  (K A-frags: 4 b128)
//  phase 2: wave w computes O^T[d-slice w*32..+31][all 64 q]   (V A: 4, P B: 8 b128)
// P is a SHARED [64 q][64 kv] buffer (16B-granule XOR swizzle, <=2-way on all
// accesses); one extra barrier between phases. Raw exp softmax (|S|<=15.36),
// per-lane l partials, one LDS exchange at the end. K/V double-buffered GLL16.
__global__ __launch_bounds__(256, 2) void flash_attn(
    const bf16* __restrict__ qn, const bf16* __restrict__ kn,
    const bf16* __restrict__ vt, bf16* __restrict__ y) {
  const int halfg = blockIdx.x >> 8;
  const int idx = blockIdx.x & 255;
  const int h = idx & 7;
  const int p = idx >> 3;
  const int qtile = halfg ? p : 63 - p;
  const int tid = threadIdx.x;
  const int wave = tid >> 6, lane = tid & 63;
  const int ln15 = lane & 15, quad = lane >> 4;
  const int ln7 = ln15 & 7;

  __shared__ __align__(16) bf16 Ks[2 * 64 * 128];  // [buf][kv][16 gran], ^ (kv&15)
  __shared__ __align__(16) bf16 Vs[2 * 128 * 64];  // [buf][d][8 gran],  ^ (d&7)
  __shared__ __align__(16) bf16 P[64 * 64];        // [q][8 gran], ^ (q&7)
  __shared__ float rsb[4][64];

  const int q0 = qtile * 64;
  const int nkv = qtile + 1;

  // Q B-frags for all 4 n-tiles (B[k=d][n=q]; identical across waves).
  bf16x8 qf[4][4];
#pragma unroll
  for (int nf = 0; nf < 4; ++nf) {
    const bf16* qb = qn + (size_t)(q0 + nf * 16 + ln15) * 1024 + h * 128 + quad * 8;
#pragma unroll
    for (int ks = 0; ks < 4; ++ks) qf[nf][ks] = *(const bf16x8*)(qb + ks * 32);
  }

  f32x4 acc_o[2][4] = {};
  float rs[4] = {0.f, 0.f, 0.f, 0.f};

  auto prefetch = [&](int kt, int buf) {
    const int kv0 = kt * 64;
    bf16* ks = Ks + buf * (64 * 128);
    bf16* vs = Vs + buf * (128 * 64);
#pragma unroll
    for (int jj = 0; jj < 4; ++jj) {  // K tile: 64 rows x 16 granules
      int gbase = jj * 256 + wave * 64;
      int g = gbase + lane;
      int r = g >> 4, c = (g & 15) ^ (r & 15);
      GLL16(kn + (size_t)(kv0 + r) * 1024 + h * 128 + c * 8,
            ks + (size_t)gbase * 8);
    }
#pragma unroll
    for (int jj = 0; jj < 4; ++jj) {  // V^T tile: 128 rows x 8 granules
      int gbase = jj * 256 + wave * 64;
      int g = gbase + lane;
      int d = g >> 3, c = (g & 7) ^ (d & 7);
      GLL16(vt + ((size_t)(h * 128 + d)) * 4096 + kv0 + c * 8,
            vs + (size_t)gbase * 8);
    }
  };

  prefetch(0, 0);

  for (int kt = 0; kt < nkv; ++kt) {
    const int kv0 = kt * 64;
    __syncthreads();  // K/V buf ready; prev iter's P reads done
    if (kt + 1 < nkv) prefetch(kt + 1, (kt + 1) & 1);
    const bf16* ksb = Ks + (kt & 1) * (64 * 128);
    const bf16* vsb = Vs + (kt & 1) * (128 * 64);

    // ---- phase 1: S^T[kv=w*16+..][all q] = K-slice * Q^T
    f32x4 accs[4] = {};
#pragma unroll
    for (int ks = 0; ks < 4; ++ks) {
      bf16x8 a = *(const bf16x8*)(
          ksb + ((wave * 16 + ln15) * 16 + ((ks * 4 + quad) ^ ln15)) * 8);
#pragma unroll
      for (int nf = 0; nf < 4; ++nf)
        accs[nf] =
            __builtin_amdgcn_mfma_f32_16x16x32_bf16(a, qf[nf][ks], accs[nf], 0, 0, 0);
    }

    // exp + causal mask + packed P store (4 consecutive kv at fixed q).
    const bool diag = (kt == nkv - 1);
    const int kvbase = kv0 + wave * 16 + quad * 4;
#pragma unroll
    for (int nf = 0; nf < 4; ++nf) {
      const int q = q0 + nf * 16 + ln15;
      bf16x4 pk;
#pragma unroll
      for (int r = 0; r < 4; ++r) {
        float pe = __expf(accs[nf][r]);
        if (diag && kvbase + r > q) pe = 0.f;
        rs[nf] += pe;
        pk[r] = (bf16)pe;
      }
      int gp = (wave * 2 + (quad >> 1)) ^ ln7;
      *(bf16x4*)(P + ((nf * 16 + ln15) * 8 + gp) * 8 + 4 * (quad & 1)) = pk;
    }
    __syncthreads();  // P complete before any wave reads it

    // ---- phase 2: O^T[d=w*32+..][all q] += V^T-slice * P^T
#pragma unroll
    for (int ks2 = 0; ks2 < 2; ++ks2) {
      bf16x8 pf[4];
#pragma unroll
      for (int nf = 0; nf < 4; ++nf)
        pf[nf] = *(const bf16x8*)(
            P + ((nf * 16 + ln15) * 8 + ((ks2 * 4 + quad) ^ ln7)) * 8);
#pragma unroll
      for (int mf = 0; mf < 2; ++mf) {
        bf16x8 a = *(const bf16x8*)(
            vsb + ((wave * 32 + mf * 16 + ln15) * 8 + ((ks2 * 4 + quad) ^ ln7)) * 8);
#pragma unroll
        for (int nf = 0; nf < 4; ++nf)
          acc_o[mf][nf] =
              __builtin_amdgcn_mfma_f32_16x16x32_bf16(a, pf[nf], acc_o[mf][nf], 0, 0, 0);
      }
    }
  }

  // l(q): reduce per-lane partials over quads, then across waves via LDS.
#pragma unroll
  for (int nf = 0; nf < 4; ++nf) {
    rs[nf] += __shfl_xor(rs[nf], 16, 64);
    rs[nf] += __shfl_xor(rs[nf], 32, 64);
  }
  if (lane < 16) {
#pragma unroll
    for (int nf = 0; nf < 4; ++nf) rsb[wave][nf * 16 + ln15] = rs[nf];
  }
  __syncthreads();
  float inv[4];
#pragma unroll
  for (int nf = 0; nf < 4; ++nf)
    inv[nf] = 1.0f / (rsb[0][nf * 16 + ln15] + rsb[1][nf * 16 + ln15] +
                      rsb[2][nf * 16 + ln15] + rsb[3][nf * 16 + ln15]);

  // O^T C-layout: d = w*32 + mf*16 + quad*4 + r, q = nf*16 + ln15.
#pragma unroll
  for (int mf = 0; mf < 2; ++mf)
#pragma unroll
    for (int nf = 0; nf < 4; ++nf) {
      bf16x4 o;
#pragma unroll
      for (int r = 0; r < 4; ++r) o[r] = (bf16)(acc_o[mf][nf][r] * inv[nf]);
      *(bf16x4*)(y + (size_t)(q0 + nf * 16 + ln15) * 1024 + h * 128 +
                 wave * 32 + mf * 16 + quad * 4) = o;
    }
}

// ---------------------------------------------------------------- launch
extern "C" void kernel_launch(void* const* d_in, const int* in_sizes, int n_in,
                              void* d_out, int out_size, void* d_ws,
                              size_t ws_size, hipStream_t stream) {
  const float* x       = (const float*)d_in[0];  // [1,4096,1024]
  const float* ve      = (const float*)d_in[1];  // [1,4096,1024]
  const float* qkv_w   = (const float*)d_in[2];  // [3,1024,1024]
  const float* lambdas = (const float*)d_in[3];  // [2]
  const float* c_proj  = (const float*)d_in[4];  // [1024,1024]
  float* out = (float*)d_out;                    // [1,4096,1024] fp32

  char* ws = (char*)d_ws;
  bf16* qkv   = (bf16*)ws;                    // 4096*3072 bf16 = 24 MiB
  bf16* xbf   = (bf16*)(ws + 25165824);       // 8 MiB
  bf16* wqkv  = (bf16*)(ws + 33554432);       // 6 MiB
  bf16* wproj = (bf16*)(ws + 39845888);       // 2 MiB
  bf16* qn    = (bf16*)(ws + 41943040);       // 8 MiB
  bf16* kn    = (bf16*)(ws + 50331648);       // 8 MiB
  bf16* vt    = (bf16*)(ws + 58720256);       // 8 MiB  [H][128][T]
  bf16* yb    = (bf16*)(ws + 67108864);       // 8 MiB  (total 72 MiB)

  cast3_f32_bf16<<<2048, 256, 0, stream>>>(x, xbf, 4194304 / 4, qkv_w, wqkv,
                                           3145728 / 4, c_proj, wproj,
                                           1048576 / 4);

  gemm_bt<1024, 3072, bf16><<<dim3(24, 32), 256, 0, stream>>>(xbf, wqkv, qkv);

  qkv_post<<<dim3(8, 64), 256, 0, stream>>>(qkv, ve, lambdas, qn, kn, vt);

  flash_attn<<<512, 256, 0, stream>>>(qn, kn, vt, yb);

  gemm_bt<1024, 1024, float><<<dim3(8, 32), 256, 0, stream>>>(yb, wproj, out);
}